// Round 11
// baseline (359.808 us; speedup 1.0000x reference)
//
#include <hip/hip_runtime.h>

#define NSTEPS 64

typedef __attribute__((ext_vector_type(4))) float float4_;     // 4 fp32 (MFMA C/D)
typedef __attribute__((ext_vector_type(2))) __fp16 half2_;     // packed f16
typedef __attribute__((ext_vector_type(8))) __fp16 half8_;     // f16 MFMA A/B operand

__device__ __forceinline__ half2_ relu_pk_f16(float a, float b) {
    half2_ h = __builtin_amdgcn_cvt_pkrtz(a, b);               // v_cvt_pkrtz_f16_f32
    return __builtin_elementwise_max(h, (half2_)(__fp16)0);    // v_pk_max_f16
}

// Opaque register pin: forces x to live in an arch VGPR and forbids the
// compiler from rematerializing/reloading it later (R10 post-mortem:
// VGPR_Count=52 < persistent live set => weights were stashed/reloaded
// per stage, ~2.4x VALU bloat).
#define PIN32(x) do { \
    unsigned _u = __builtin_bit_cast(unsigned, (x)); \
    asm volatile("" : "+v"(_u)); \
    (x) = __builtin_bit_cast(__typeof__(x), _u); \
} while (0)

// MFMA 16x16x32 layouts (HW-verified R4/R5, dtype-independent per guide):
//   A[m][k]: m=lane&15, k=(lane>>4)*8+j ; B[k][n]: n=lane&15, k=(lane>>4)*8+j
//   D[m][n]: m=(lane>>4)*4+reg, n=lane&15
// Transposed trick (R5): D = mfma(W2^T, h1) -> lane holds h2^T rows
// j2 = quad*4+reg (+16 for 2nd MFMA) for its own sample col n=lane&15.
// R7: TWO independent 16-row groups per wave for ILP across stall points.
// R10: all-f16 datapath — L1 via fdot2 (bias folded), h1 stays f16, f16 MFMA.
// R11: pin persistent operands in VGPRs (see PIN32).
__global__ __launch_bounds__(256, 4)
void ode_rk4_mfma(const float* __restrict__ x,
                  const float* __restrict__ samples,
                  const float* __restrict__ w1, const float* __restrict__ b1,
                  const float* __restrict__ w2, const float* __restrict__ b2,
                  const float* __restrict__ w3, const float* __restrict__ b3,
                  const float* __restrict__ w_out, const float* __restrict__ b_out,
                  float* __restrict__ out, int B)
{
    const int lane  = threadIdx.x & 63;
    const int w     = threadIdx.x >> 6;
    const int col16 = lane & 15;
    const int quad  = lane >> 4;

    const int rowBase = (blockIdx.x * 4 + w) * 32;
    const int rA = rowBase + col16;          // group A row
    const int rB = rA + 16;                  // group B row

    // ---- persistent operands (built once; reused 1024 evals) ----
    // layer1 weight pairs for fdot2: w1p = (w1[0][j], w1[1][j]), w1q = (w1[2][j], b1[j])
    half2_ w1p[8], w1q[8];
#pragma unroll
    for (int jl = 0; jl < 8; ++jl) {
        int j = quad * 8 + jl;
        w1p[jl] = (half2_){(__fp16)w1[0 * 32 + j], (__fp16)w1[1 * 32 + j]};
        w1q[jl] = (half2_){(__fp16)w1[2 * 32 + j], (__fp16)b1[j]};
    }
    // W2^T A-frags in f16: A[m=j2][k=i1] = w2[i1*32+j2]
    union { half2_ h2[4]; half8_ h8; } W2Ta, W2Tb;
#pragma unroll
    for (int p = 0; p < 4; ++p) {
        int i1 = quad * 8 + 2 * p;
        W2Ta.h2[p] = (half2_){(__fp16)w2[i1 * 32 + col16], (__fp16)w2[(i1 + 1) * 32 + col16]};
        W2Tb.h2[p] = (half2_){(__fp16)w2[i1 * 32 + col16 + 16], (__fp16)w2[(i1 + 1) * 32 + col16 + 16]};
    }
    float4_ Cb2a, Cb2b;  // bias C-frags
#pragma unroll
    for (int r = 0; r < 4; ++r) {
        Cb2a[r] = b2[quad * 4 + r];
        Cb2b[r] = b2[16 + quad * 4 + r];
    }
    // layer3 weights as f16 pairs matching h pairs (j2, j2+1)
    half2_ w3h[3][4];
#pragma unroll
    for (int d = 0; d < 3; ++d) {
#pragma unroll
        for (int p = 0; p < 4; ++p) {
            int j0 = ((p >> 1) ? 16 : 0) + quad * 4 + (p & 1) * 2;
            w3h[d][p] = (half2_){(__fp16)w3[j0 * 3 + d], (__fp16)w3[(j0 + 1) * 3 + d]};
        }
    }

    // ---- pin all persistent operands into arch VGPRs ----
#pragma unroll
    for (int i = 0; i < 8; ++i) { PIN32(w1p[i]); PIN32(w1q[i]); }
#pragma unroll
    for (int p = 0; p < 4; ++p) { PIN32(W2Ta.h2[p]); PIN32(W2Tb.h2[p]); }
#pragma unroll
    for (int r = 0; r < 4; ++r) {
        float t;
        t = Cb2a[r]; asm volatile("" : "+v"(t)); Cb2a[r] = t;
        t = Cb2b[r]; asm volatile("" : "+v"(t)); Cb2b[r] = t;
    }
#pragma unroll
    for (int d = 0; d < 3; ++d)
#pragma unroll
        for (int p = 0; p < 4; ++p) PIN32(w3h[d][p]);

    // ---- scalars ----
    const float maxT = samples[7];
    const float dt   = maxT / 64.0f;
    const float dt2  = 0.5f * dt;
    const float dt6  = dt / 6.0f;

    int sidx[8];
    unsigned long long smask = 0ull;
#pragma unroll
    for (int j = 0; j < 8; ++j) {
        int id = (int)rintf(samples[j] / dt) - 1;   // jnp.round = RNE
        id = id < 0 ? 0 : (id > NSTEPS - 1 ? NSTEPS - 1 : id);
        id = __builtin_amdgcn_readfirstlane(id);    // wave-uniform -> SGPR
        sidx[j] = id;
        smask |= 1ull << id;
    }
    const float wo0 = w_out[0], wo1 = w_out[1], wo2 = w_out[2];
    const float bo  = b_out[0];
    const float b30 = b3[0], b31 = b3[1], b32 = b3[2];

    float yA0 = x[(size_t)rA * 3 + 0], yA1 = x[(size_t)rA * 3 + 1], yA2 = x[(size_t)rA * 3 + 2];
    float yB0 = x[(size_t)rB * 3 + 0], yB1 = x[(size_t)rB * 3 + 1], yB2 = x[(size_t)rB * 3 + 2];

#pragma unroll 1
    for (int s = 0; s < NSTEPS; ++s) {
        float accA0 = 0.f, accA1 = 0.f, accA2 = 0.f;
        float accB0 = 0.f, accB1 = 0.f, accB2 = 0.f;
        float aA0 = yA0, aA1 = yA1, aA2 = yA2;
        float aB0 = yB0, aB1 = yB1, aB2 = yB2;

#pragma unroll 1
        for (int st = 0; st < 4; ++st) {
            // ---- layer1 via fdot2 (bias folded), both groups ----
            half2_ aA01 = __builtin_amdgcn_cvt_pkrtz(aA0, aA1);
            half2_ aA2o = __builtin_amdgcn_cvt_pkrtz(aA2, 1.0f);
            half2_ aB01 = __builtin_amdgcn_cvt_pkrtz(aB0, aB1);
            half2_ aB2o = __builtin_amdgcn_cvt_pkrtz(aB2, 1.0f);
            float hfA[8], hfB[8];
#pragma unroll
            for (int jl = 0; jl < 8; ++jl) {
                hfA[jl] = __builtin_amdgcn_fdot2(aA01, w1p[jl],
                          __builtin_amdgcn_fdot2(aA2o, w1q[jl], 0.f, false), false);
                hfB[jl] = __builtin_amdgcn_fdot2(aB01, w1p[jl],
                          __builtin_amdgcn_fdot2(aB2o, w1q[jl], 0.f, false), false);
            }
            union { half2_ h2[4]; half8_ h8; } A2A, A2B;
#pragma unroll
            for (int p = 0; p < 4; ++p) {
                A2A.h2[p] = relu_pk_f16(hfA[2 * p], hfA[2 * p + 1]);
                A2B.h2[p] = relu_pk_f16(hfB[2 * p], hfB[2 * p + 1]);
            }

            // ---- layer2 transposed: 4 independent f16 MFMAs ----
            float4_ DA0 = __builtin_amdgcn_mfma_f32_16x16x32_f16(W2Ta.h8, A2A.h8, Cb2a, 0, 0, 0);
            float4_ DA1 = __builtin_amdgcn_mfma_f32_16x16x32_f16(W2Tb.h8, A2A.h8, Cb2b, 0, 0, 0);
            float4_ DB0 = __builtin_amdgcn_mfma_f32_16x16x32_f16(W2Ta.h8, A2B.h8, Cb2a, 0, 0, 0);
            float4_ DB1 = __builtin_amdgcn_mfma_f32_16x16x32_f16(W2Tb.h8, A2B.h8, Cb2b, 0, 0, 0);

            // ---- relu -> packed f16 pairs ----
            half2_ hA[4], hB[4];
            hA[0] = relu_pk_f16(DA0[0], DA0[1]); hA[1] = relu_pk_f16(DA0[2], DA0[3]);
            hA[2] = relu_pk_f16(DA1[0], DA1[1]); hA[3] = relu_pk_f16(DA1[2], DA1[3]);
            hB[0] = relu_pk_f16(DB0[0], DB0[1]); hB[1] = relu_pk_f16(DB0[2], DB0[3]);
            hB[2] = relu_pk_f16(DB1[0], DB1[1]); hB[3] = relu_pk_f16(DB1[2], DB1[3]);

            // ---- layer3 via fdot2 (12 per group) ----
            float pA0 = 0.f, pA1 = 0.f, pA2 = 0.f;
            float pB0 = 0.f, pB1 = 0.f, pB2 = 0.f;
#pragma unroll
            for (int p = 0; p < 4; ++p) {
                pA0 = __builtin_amdgcn_fdot2(hA[p], w3h[0][p], pA0, false);
                pA1 = __builtin_amdgcn_fdot2(hA[p], w3h[1][p], pA1, false);
                pA2 = __builtin_amdgcn_fdot2(hA[p], w3h[2][p], pA2, false);
                pB0 = __builtin_amdgcn_fdot2(hB[p], w3h[0][p], pB0, false);
                pB1 = __builtin_amdgcn_fdot2(hB[p], w3h[1][p], pB1, false);
                pB2 = __builtin_amdgcn_fdot2(hB[p], w3h[2][p], pB2, false);
            }

            // ---- reduce across the 4 quads (A and B chains interleave) ----
            pA0 += __shfl_xor(pA0, 16); pB0 += __shfl_xor(pB0, 16);
            pA1 += __shfl_xor(pA1, 16); pB1 += __shfl_xor(pB1, 16);
            pA2 += __shfl_xor(pA2, 16); pB2 += __shfl_xor(pB2, 16);
            pA0 += __shfl_xor(pA0, 32); pB0 += __shfl_xor(pB0, 32);
            pA1 += __shfl_xor(pA1, 32); pB1 += __shfl_xor(pB1, 32);
            pA2 += __shfl_xor(pA2, 32); pB2 += __shfl_xor(pB2, 32);
            float kA0 = pA0 + b30, kA1 = pA1 + b31, kA2 = pA2 + b32;
            float kB0 = pB0 + b30, kB1 = pB1 + b31, kB2 = pB2 + b32;

            const float ca = (st == 1 || st == 2) ? 2.0f : 1.0f;
            accA0 = fmaf(ca, kA0, accA0); accA1 = fmaf(ca, kA1, accA1); accA2 = fmaf(ca, kA2, accA2);
            accB0 = fmaf(ca, kB0, accB0); accB1 = fmaf(ca, kB1, accB1); accB2 = fmaf(ca, kB2, accB2);
            const float ci = (st == 2) ? dt : dt2;
            aA0 = fmaf(ci, kA0, yA0); aA1 = fmaf(ci, kA1, yA1); aA2 = fmaf(ci, kA2, yA2);
            aB0 = fmaf(ci, kB0, yB0); aB1 = fmaf(ci, kB1, yB1); aB2 = fmaf(ci, kB2, yB2);
        }
        yA0 = fmaf(dt6, accA0, yA0); yA1 = fmaf(dt6, accA1, yA1); yA2 = fmaf(dt6, accA2, yA2);
        yB0 = fmaf(dt6, accB0, yB0); yB1 = fmaf(dt6, accB1, yB1); yB2 = fmaf(dt6, accB2, yB2);

        // wave-uniform SALU fast path: most steps store nothing
        if ((smask >> s) & 1ull) {
            if (quad == 0) {
#pragma unroll
                for (int j = 0; j < 8; ++j) {
                    if (sidx[j] == s) {
                        out[(size_t)j * B + rA] = fmaf(yA2, wo2, fmaf(yA1, wo1, fmaf(yA0, wo0, bo)));
                        out[(size_t)j * B + rB] = fmaf(yB2, wo2, fmaf(yB1, wo1, fmaf(yB0, wo0, bo)));
                    }
                }
            }
        }
    }
}

extern "C" void kernel_launch(void* const* d_in, const int* in_sizes, int n_in,
                              void* d_out, int out_size, void* d_ws, size_t ws_size,
                              hipStream_t stream) {
    const float* x       = (const float*)d_in[0];
    const float* samples = (const float*)d_in[1];
    const float* w1      = (const float*)d_in[2];
    const float* b1      = (const float*)d_in[3];
    const float* w2      = (const float*)d_in[4];
    const float* b2      = (const float*)d_in[5];
    const float* w3      = (const float*)d_in[6];
    const float* b3      = (const float*)d_in[7];
    const float* w_out   = (const float*)d_in[8];
    const float* b_out   = (const float*)d_in[9];
    float* out = (float*)d_out;

    const int B = in_sizes[0] / 3;           // 131072
    const int rowsPerBlock = 128;            // 4 waves x 32 rows (2 groups of 16)
    const int grid = (B + rowsPerBlock - 1) / rowsPerBlock;
    ode_rk4_mfma<<<grid, 256, 0, stream>>>(
        x, samples, w1, b1, w2, b2, w3, b3, w_out, b_out, out, B);
}

// Round 12
// 358.341 us; speedup vs baseline: 1.0041x; 1.0041x over previous
//
#include <hip/hip_runtime.h>

#define NSTEPS 64

typedef __attribute__((ext_vector_type(4))) float float4_;     // 4 fp32 (MFMA C/D)
typedef __attribute__((ext_vector_type(2))) __fp16 half2_;     // packed f16
typedef __attribute__((ext_vector_type(8))) __fp16 half8_;     // f16 MFMA A/B operand

__device__ __forceinline__ half2_ relu_pk_f16(float a, float b) {
    half2_ h = __builtin_amdgcn_cvt_pkrtz(a, b);               // v_cvt_pkrtz_f16_f32
    return __builtin_elementwise_max(h, (half2_)(__fp16)0);    // v_pk_max_f16
}

// Loop-carried opaque pin: zero instructions, but value becomes an in/out of
// unanalyzable asm EVERY iteration -> no remat/reload of the original load,
// must stay live in an arch VGPR ("v" constraint, not AGPR) across the body
// and the backedge. (R11 pinned before the loop -> compiler re-stashed inside;
// VGPR_Count stayed 52 and ~170 hidden ops/stage remained.)
#define PIN32(x) do { \
    unsigned _u = __builtin_bit_cast(unsigned, (x)); \
    asm volatile("" : "+v"(_u)); \
    (x) = __builtin_bit_cast(__typeof__(x), _u); \
} while (0)

// MFMA 16x16x32 layouts (HW-verified R4/R5, dtype-independent per guide):
//   A[m][k]: m=lane&15, k=(lane>>4)*8+j ; B[k][n]: n=lane&15, k=(lane>>4)*8+j
//   D[m][n]: m=(lane>>4)*4+reg, n=lane&15
// Transposed trick (R5): D = mfma(W2^T, h1) -> lane holds h2^T rows
// j2 = quad*4+reg (+16 for 2nd MFMA) for its own sample col n=lane&15.
// R7: TWO independent 16-row groups per wave for ILP across stall points.
// R10: all-f16 datapath — L1 via fdot2 (bias folded), h1 stays f16, f16 MFMA.
// R12: loop-carried pins + fully-unrolled RK4 stage loop.
__global__ __launch_bounds__(256, 4)
void ode_rk4_mfma(const float* __restrict__ x,
                  const float* __restrict__ samples,
                  const float* __restrict__ w1, const float* __restrict__ b1,
                  const float* __restrict__ w2, const float* __restrict__ b2,
                  const float* __restrict__ w3, const float* __restrict__ b3,
                  const float* __restrict__ w_out, const float* __restrict__ b_out,
                  float* __restrict__ out, int B)
{
    const int lane  = threadIdx.x & 63;
    const int w     = threadIdx.x >> 6;
    const int col16 = lane & 15;
    const int quad  = lane >> 4;

    const int rowBase = (blockIdx.x * 4 + w) * 32;
    const int rA = rowBase + col16;          // group A row
    const int rB = rA + 16;                  // group B row

    // ---- persistent operands (built once; reused 1024 evals) ----
    // layer1 weight pairs for fdot2: w1p = (w1[0][j], w1[1][j]), w1q = (w1[2][j], b1[j])
    half2_ w1p[8], w1q[8];
#pragma unroll
    for (int jl = 0; jl < 8; ++jl) {
        int j = quad * 8 + jl;
        w1p[jl] = (half2_){(__fp16)w1[0 * 32 + j], (__fp16)w1[1 * 32 + j]};
        w1q[jl] = (half2_){(__fp16)w1[2 * 32 + j], (__fp16)b1[j]};
    }
    // W2^T A-frags in f16: A[m=j2][k=i1] = w2[i1*32+j2]
    union { half2_ h2[4]; half8_ h8; } W2Ta, W2Tb;
#pragma unroll
    for (int p = 0; p < 4; ++p) {
        int i1 = quad * 8 + 2 * p;
        W2Ta.h2[p] = (half2_){(__fp16)w2[i1 * 32 + col16], (__fp16)w2[(i1 + 1) * 32 + col16]};
        W2Tb.h2[p] = (half2_){(__fp16)w2[i1 * 32 + col16 + 16], (__fp16)w2[(i1 + 1) * 32 + col16 + 16]};
    }
    float4_ Cb2a, Cb2b;  // bias C-frags
#pragma unroll
    for (int r = 0; r < 4; ++r) {
        Cb2a[r] = b2[quad * 4 + r];
        Cb2b[r] = b2[16 + quad * 4 + r];
    }
    // layer3 weights as f16 pairs matching h pairs (j2, j2+1)
    half2_ w3h[3][4];
#pragma unroll
    for (int d = 0; d < 3; ++d) {
#pragma unroll
        for (int p = 0; p < 4; ++p) {
            int j0 = ((p >> 1) ? 16 : 0) + quad * 4 + (p & 1) * 2;
            w3h[d][p] = (half2_){(__fp16)w3[j0 * 3 + d], (__fp16)w3[(j0 + 1) * 3 + d]};
        }
    }

    // ---- scalars ----
    const float maxT = samples[7];
    const float dt   = maxT / 64.0f;
    const float dt2  = 0.5f * dt;
    const float dt6  = dt / 6.0f;

    int sidx[8];
    unsigned long long smask = 0ull;
#pragma unroll
    for (int j = 0; j < 8; ++j) {
        int id = (int)rintf(samples[j] / dt) - 1;   // jnp.round = RNE
        id = id < 0 ? 0 : (id > NSTEPS - 1 ? NSTEPS - 1 : id);
        id = __builtin_amdgcn_readfirstlane(id);    // wave-uniform -> SGPR
        sidx[j] = id;
        smask |= 1ull << id;
    }
    const float wo0 = w_out[0], wo1 = w_out[1], wo2 = w_out[2];
    const float bo  = b_out[0];
    const float b30 = b3[0], b31 = b3[1], b32 = b3[2];

    float yA0 = x[(size_t)rA * 3 + 0], yA1 = x[(size_t)rA * 3 + 1], yA2 = x[(size_t)rA * 3 + 2];
    float yB0 = x[(size_t)rB * 3 + 0], yB1 = x[(size_t)rB * 3 + 1], yB2 = x[(size_t)rB * 3 + 2];

#pragma unroll 1
    for (int s = 0; s < NSTEPS; ++s) {
        // ---- loop-carried pins: weights must stay in arch VGPRs ----
#pragma unroll
        for (int i = 0; i < 8; ++i) { PIN32(w1p[i]); PIN32(w1q[i]); }
#pragma unroll
        for (int p = 0; p < 4; ++p) { PIN32(W2Ta.h2[p]); PIN32(W2Tb.h2[p]); }
#pragma unroll
        for (int r = 0; r < 4; ++r) {
            float t;
            t = Cb2a[r]; asm volatile("" : "+v"(t)); Cb2a[r] = t;
            t = Cb2b[r]; asm volatile("" : "+v"(t)); Cb2b[r] = t;
        }
#pragma unroll
        for (int d = 0; d < 3; ++d)
#pragma unroll
            for (int p = 0; p < 4; ++p) PIN32(w3h[d][p]);

        float accA0 = 0.f, accA1 = 0.f, accA2 = 0.f;
        float accB0 = 0.f, accB1 = 0.f, accB2 = 0.f;
        float aA0 = yA0, aA1 = yA1, aA2 = yA2;
        float aB0 = yB0, aB1 = yB1, aB2 = yB2;

        // RK4 stage loop FULLY UNROLLED (ca/ci become literals, no cndmask)
#pragma unroll
        for (int st = 0; st < 4; ++st) {
            // ---- layer1 via fdot2 (bias folded), both groups ----
            half2_ aA01 = __builtin_amdgcn_cvt_pkrtz(aA0, aA1);
            half2_ aA2o = __builtin_amdgcn_cvt_pkrtz(aA2, 1.0f);
            half2_ aB01 = __builtin_amdgcn_cvt_pkrtz(aB0, aB1);
            half2_ aB2o = __builtin_amdgcn_cvt_pkrtz(aB2, 1.0f);
            float hfA[8], hfB[8];
#pragma unroll
            for (int jl = 0; jl < 8; ++jl) {
                hfA[jl] = __builtin_amdgcn_fdot2(aA01, w1p[jl],
                          __builtin_amdgcn_fdot2(aA2o, w1q[jl], 0.f, false), false);
                hfB[jl] = __builtin_amdgcn_fdot2(aB01, w1p[jl],
                          __builtin_amdgcn_fdot2(aB2o, w1q[jl], 0.f, false), false);
            }
            union { half2_ h2[4]; half8_ h8; } A2A, A2B;
#pragma unroll
            for (int p = 0; p < 4; ++p) {
                A2A.h2[p] = relu_pk_f16(hfA[2 * p], hfA[2 * p + 1]);
                A2B.h2[p] = relu_pk_f16(hfB[2 * p], hfB[2 * p + 1]);
            }

            // ---- layer2 transposed: 4 independent f16 MFMAs ----
            float4_ DA0 = __builtin_amdgcn_mfma_f32_16x16x32_f16(W2Ta.h8, A2A.h8, Cb2a, 0, 0, 0);
            float4_ DA1 = __builtin_amdgcn_mfma_f32_16x16x32_f16(W2Tb.h8, A2A.h8, Cb2b, 0, 0, 0);
            float4_ DB0 = __builtin_amdgcn_mfma_f32_16x16x32_f16(W2Ta.h8, A2B.h8, Cb2a, 0, 0, 0);
            float4_ DB1 = __builtin_amdgcn_mfma_f32_16x16x32_f16(W2Tb.h8, A2B.h8, Cb2b, 0, 0, 0);

            // ---- relu -> packed f16 pairs ----
            half2_ hA[4], hB[4];
            hA[0] = relu_pk_f16(DA0[0], DA0[1]); hA[1] = relu_pk_f16(DA0[2], DA0[3]);
            hA[2] = relu_pk_f16(DA1[0], DA1[1]); hA[3] = relu_pk_f16(DA1[2], DA1[3]);
            hB[0] = relu_pk_f16(DB0[0], DB0[1]); hB[1] = relu_pk_f16(DB0[2], DB0[3]);
            hB[2] = relu_pk_f16(DB1[0], DB1[1]); hB[3] = relu_pk_f16(DB1[2], DB1[3]);

            // ---- layer3 via fdot2 (12 per group) ----
            float pA0 = 0.f, pA1 = 0.f, pA2 = 0.f;
            float pB0 = 0.f, pB1 = 0.f, pB2 = 0.f;
#pragma unroll
            for (int p = 0; p < 4; ++p) {
                pA0 = __builtin_amdgcn_fdot2(hA[p], w3h[0][p], pA0, false);
                pA1 = __builtin_amdgcn_fdot2(hA[p], w3h[1][p], pA1, false);
                pA2 = __builtin_amdgcn_fdot2(hA[p], w3h[2][p], pA2, false);
                pB0 = __builtin_amdgcn_fdot2(hB[p], w3h[0][p], pB0, false);
                pB1 = __builtin_amdgcn_fdot2(hB[p], w3h[1][p], pB1, false);
                pB2 = __builtin_amdgcn_fdot2(hB[p], w3h[2][p], pB2, false);
            }

            // ---- reduce across the 4 quads (A and B chains interleave) ----
            pA0 += __shfl_xor(pA0, 16); pB0 += __shfl_xor(pB0, 16);
            pA1 += __shfl_xor(pA1, 16); pB1 += __shfl_xor(pB1, 16);
            pA2 += __shfl_xor(pA2, 16); pB2 += __shfl_xor(pB2, 16);
            pA0 += __shfl_xor(pA0, 32); pB0 += __shfl_xor(pB0, 32);
            pA1 += __shfl_xor(pA1, 32); pB1 += __shfl_xor(pB1, 32);
            pA2 += __shfl_xor(pA2, 32); pB2 += __shfl_xor(pB2, 32);
            float kA0 = pA0 + b30, kA1 = pA1 + b31, kA2 = pA2 + b32;
            float kB0 = pB0 + b30, kB1 = pB1 + b31, kB2 = pB2 + b32;

            const float ca = (st == 1 || st == 2) ? 2.0f : 1.0f;
            accA0 = fmaf(ca, kA0, accA0); accA1 = fmaf(ca, kA1, accA1); accA2 = fmaf(ca, kA2, accA2);
            accB0 = fmaf(ca, kB0, accB0); accB1 = fmaf(ca, kB1, accB1); accB2 = fmaf(ca, kB2, accB2);
            const float ci = (st == 2) ? dt : dt2;
            aA0 = fmaf(ci, kA0, yA0); aA1 = fmaf(ci, kA1, yA1); aA2 = fmaf(ci, kA2, yA2);
            aB0 = fmaf(ci, kB0, yB0); aB1 = fmaf(ci, kB1, yB1); aB2 = fmaf(ci, kB2, yB2);
        }
        yA0 = fmaf(dt6, accA0, yA0); yA1 = fmaf(dt6, accA1, yA1); yA2 = fmaf(dt6, accA2, yA2);
        yB0 = fmaf(dt6, accB0, yB0); yB1 = fmaf(dt6, accB1, yB1); yB2 = fmaf(dt6, accB2, yB2);

        // wave-uniform SALU fast path: most steps store nothing
        if ((smask >> s) & 1ull) {
            if (quad == 0) {
#pragma unroll
                for (int j = 0; j < 8; ++j) {
                    if (sidx[j] == s) {
                        out[(size_t)j * B + rA] = fmaf(yA2, wo2, fmaf(yA1, wo1, fmaf(yA0, wo0, bo)));
                        out[(size_t)j * B + rB] = fmaf(yB2, wo2, fmaf(yB1, wo1, fmaf(yB0, wo0, bo)));
                    }
                }
            }
        }
    }
}

extern "C" void kernel_launch(void* const* d_in, const int* in_sizes, int n_in,
                              void* d_out, int out_size, void* d_ws, size_t ws_size,
                              hipStream_t stream) {
    const float* x       = (const float*)d_in[0];
    const float* samples = (const float*)d_in[1];
    const float* w1      = (const float*)d_in[2];
    const float* b1      = (const float*)d_in[3];
    const float* w2      = (const float*)d_in[4];
    const float* b2      = (const float*)d_in[5];
    const float* w3      = (const float*)d_in[6];
    const float* b3      = (const float*)d_in[7];
    const float* w_out   = (const float*)d_in[8];
    const float* b_out   = (const float*)d_in[9];
    float* out = (float*)d_out;

    const int B = in_sizes[0] / 3;           // 131072
    const int rowsPerBlock = 128;            // 4 waves x 32 rows (2 groups of 16)
    const int grid = (B + rowsPerBlock - 1) / rowsPerBlock;
    ode_rk4_mfma<<<grid, 256, 0, stream>>>(
        x, samples, w1, b1, w2, b2, w3, b3, w_out, b_out, out, B);
}

// Round 13
// 312.728 us; speedup vs baseline: 1.1505x; 1.1459x over previous
//
#include <hip/hip_runtime.h>

#define NSTEPS 64

typedef __attribute__((ext_vector_type(16))) float float16_;   // 32x32 MFMA C/D
typedef __attribute__((ext_vector_type(2))) __fp16 half2_;     // packed f16
typedef __attribute__((ext_vector_type(8))) __fp16 half8_;     // f16 MFMA A/B operand

__device__ __forceinline__ half2_ relu_pk_f16(float a, float b) {
    half2_ h = __builtin_amdgcn_cvt_pkrtz(a, b);               // v_cvt_pkrtz_f16_f32
    return __builtin_elementwise_max(h, (half2_)(__fp16)0);    // v_pk_max_f16
}

// R13: 32x32x16 f16 MFMA restructure.
//   A[m][k]: m=lane&31, k=(lane>>5)*8+j      (two K-halves -> 2 chained MFMAs)
//   B[k][n]: n=lane&31, k=(lane>>5)*8+j      (same register mapping as A)
//   C/D[r][c]: c=lane&31, r=(reg&3)+8*(reg>>2)+4*(lane>>5)    [HW: m74/m101]
// Transposed trick: D = mfma(W2^T, h1) -> lane holds h2^T rows
// j2 = (reg&3)+8*(reg>>2)+4*half for its own sample row c=lane&31.
// Row coverage split across only TWO lanes (lane, lane^32) -> ONE shfl round.
// 64 rows/wave (2 groups of 32) at (256,2): 256-VGPR cap -> no AGPR stash
// (R10-R12: 128-cap forced weights into AGPRs, hidden accvgpr traffic).
__global__ __launch_bounds__(256, 2)
void ode_rk4_mfma(const float* __restrict__ x,
                  const float* __restrict__ samples,
                  const float* __restrict__ w1, const float* __restrict__ b1,
                  const float* __restrict__ w2, const float* __restrict__ b2,
                  const float* __restrict__ w3, const float* __restrict__ b3,
                  const float* __restrict__ w_out, const float* __restrict__ b_out,
                  float* __restrict__ out, int B)
{
    const int lane  = threadIdx.x & 63;
    const int w     = threadIdx.x >> 6;
    const int col32 = lane & 31;              // this lane's sample row (mod 32)
    const int half  = lane >> 5;              // 0..1

    const int rowBase = (blockIdx.x * 4 + w) * 64;
    const int rA = rowBase + col32;           // group A row
    const int rB = rA + 32;                   // group B row

    // ---- persistent operands (built once; reused 1024 evals) ----
    // layer1 weights for fdot2, 16 columns per lane: i1 = half*8+jl (jl<8) or 16+half*8+(jl-8)
    half2_ w1p[16], w1q[16];
#pragma unroll
    for (int jl = 0; jl < 16; ++jl) {
        int i1 = (jl < 8) ? (half * 8 + jl) : (16 + half * 8 + (jl - 8));
        w1p[jl] = (half2_){(__fp16)w1[0 * 32 + i1], (__fp16)w1[1 * 32 + i1]};
        w1q[jl] = (half2_){(__fp16)w1[2 * 32 + i1], (__fp16)b1[i1]};
    }
    // W2^T A-frags: A[m=j2][k=i1] = w2[i1*32 + j2]; two K-halves
    union { half2_ h2[4]; half8_ h8; } W2T1, W2T2;
#pragma unroll
    for (int pp = 0; pp < 4; ++pp) {
        int i1 = half * 8 + 2 * pp;
        W2T1.h2[pp] = (half2_){(__fp16)w2[i1 * 32 + col32], (__fp16)w2[(i1 + 1) * 32 + col32]};
        W2T2.h2[pp] = (half2_){(__fp16)w2[(i1 + 16) * 32 + col32], (__fp16)w2[(i1 + 17) * 32 + col32]};
    }
    // bias C-frag: Cb[r] = b2[j2(r)] with j2 = (r&3)+8*(r>>2)+4*half
    float16_ Cb;
#pragma unroll
    for (int r = 0; r < 16; ++r)
        Cb[r] = b2[(r & 3) + 8 * (r >> 2) + 4 * half];
    // layer3 weights as f16 pairs matching D reg pairs: pair p -> j2_0 = 8*(p>>1)+2*(p&1)+4*half
    half2_ w3h[3][8];
#pragma unroll
    for (int d = 0; d < 3; ++d)
#pragma unroll
        for (int p = 0; p < 8; ++p) {
            int j0 = 8 * (p >> 1) + 2 * (p & 1) + 4 * half;
            w3h[d][p] = (half2_){(__fp16)w3[j0 * 3 + d], (__fp16)w3[(j0 + 1) * 3 + d]};
        }

    // ---- scalars ----
    const float maxT = samples[7];
    const float dt   = maxT / 64.0f;
    const float dt2  = 0.5f * dt;
    const float dt6  = dt / 6.0f;

    int sidx[8];
    unsigned long long smask = 0ull;
#pragma unroll
    for (int j = 0; j < 8; ++j) {
        int id = (int)rintf(samples[j] / dt) - 1;   // jnp.round = RNE
        id = id < 0 ? 0 : (id > NSTEPS - 1 ? NSTEPS - 1 : id);
        id = __builtin_amdgcn_readfirstlane(id);    // wave-uniform -> SGPR
        sidx[j] = id;
        smask |= 1ull << id;
    }
    const float wo0 = w_out[0], wo1 = w_out[1], wo2 = w_out[2];
    const float bo  = b_out[0];
    const float b30 = b3[0], b31 = b3[1], b32 = b3[2];

    float yA0 = x[(size_t)rA * 3 + 0], yA1 = x[(size_t)rA * 3 + 1], yA2 = x[(size_t)rA * 3 + 2];
    float yB0 = x[(size_t)rB * 3 + 0], yB1 = x[(size_t)rB * 3 + 1], yB2 = x[(size_t)rB * 3 + 2];

#pragma unroll 1
    for (int s = 0; s < NSTEPS; ++s) {
        float accA0 = 0.f, accA1 = 0.f, accA2 = 0.f;
        float accB0 = 0.f, accB1 = 0.f, accB2 = 0.f;
        float aA0 = yA0, aA1 = yA1, aA2 = yA2;
        float aB0 = yB0, aB1 = yB1, aB2 = yB2;

#pragma unroll
        for (int st = 0; st < 4; ++st) {
            // ---- layer1 via fdot2 (bias folded), both groups ----
            half2_ aA01 = __builtin_amdgcn_cvt_pkrtz(aA0, aA1);
            half2_ aA2o = __builtin_amdgcn_cvt_pkrtz(aA2, 1.0f);
            half2_ aB01 = __builtin_amdgcn_cvt_pkrtz(aB0, aB1);
            half2_ aB2o = __builtin_amdgcn_cvt_pkrtz(aB2, 1.0f);
            float hfA[16], hfB[16];
#pragma unroll
            for (int jl = 0; jl < 16; ++jl) {
                hfA[jl] = __builtin_amdgcn_fdot2(aA01, w1p[jl],
                          __builtin_amdgcn_fdot2(aA2o, w1q[jl], 0.f, false), false);
                hfB[jl] = __builtin_amdgcn_fdot2(aB01, w1p[jl],
                          __builtin_amdgcn_fdot2(aB2o, w1q[jl], 0.f, false), false);
            }
            // B operands: elements j of B#1 <- hf[j] (k=half*8+j), B#2 <- hf[8+j]
            union { half2_ h2[4]; half8_ h8; } B1A, B2A, B1B, B2B;
#pragma unroll
            for (int pp = 0; pp < 4; ++pp) {
                B1A.h2[pp] = relu_pk_f16(hfA[2 * pp], hfA[2 * pp + 1]);
                B2A.h2[pp] = relu_pk_f16(hfA[8 + 2 * pp], hfA[8 + 2 * pp + 1]);
                B1B.h2[pp] = relu_pk_f16(hfB[2 * pp], hfB[2 * pp + 1]);
                B2B.h2[pp] = relu_pk_f16(hfB[8 + 2 * pp], hfB[8 + 2 * pp + 1]);
            }

            // ---- layer2: two chained 32x32x16 MFMAs per group (K=32) ----
            float16_ DA = __builtin_amdgcn_mfma_f32_32x32x16_f16(W2T1.h8, B1A.h8,
                          __builtin_amdgcn_mfma_f32_32x32x16_f16(W2T2.h8, B2A.h8, Cb, 0, 0, 0), 0, 0, 0);
            float16_ DB = __builtin_amdgcn_mfma_f32_32x32x16_f16(W2T1.h8, B1B.h8,
                          __builtin_amdgcn_mfma_f32_32x32x16_f16(W2T2.h8, B2B.h8, Cb, 0, 0, 0), 0, 0, 0);

            // ---- relu -> packed f16 pairs (reg pair p matches w3h pairing) ----
            half2_ hA[8], hB[8];
#pragma unroll
            for (int p = 0; p < 8; ++p) {
                hA[p] = relu_pk_f16(DA[2 * p], DA[2 * p + 1]);
                hB[p] = relu_pk_f16(DB[2 * p], DB[2 * p + 1]);
            }

            // ---- layer3 via fdot2 (24 per group) ----
            float pA0 = 0.f, pA1 = 0.f, pA2 = 0.f;
            float pB0 = 0.f, pB1 = 0.f, pB2 = 0.f;
#pragma unroll
            for (int p = 0; p < 8; ++p) {
                pA0 = __builtin_amdgcn_fdot2(hA[p], w3h[0][p], pA0, false);
                pA1 = __builtin_amdgcn_fdot2(hA[p], w3h[1][p], pA1, false);
                pA2 = __builtin_amdgcn_fdot2(hA[p], w3h[2][p], pA2, false);
                pB0 = __builtin_amdgcn_fdot2(hB[p], w3h[0][p], pB0, false);
                pB1 = __builtin_amdgcn_fdot2(hB[p], w3h[1][p], pB1, false);
                pB2 = __builtin_amdgcn_fdot2(hB[p], w3h[2][p], pB2, false);
            }

            // ---- ONE reduction round: lane^32 holds the other K-half of this row ----
            pA0 += __shfl_xor(pA0, 32); pB0 += __shfl_xor(pB0, 32);
            pA1 += __shfl_xor(pA1, 32); pB1 += __shfl_xor(pB1, 32);
            pA2 += __shfl_xor(pA2, 32); pB2 += __shfl_xor(pB2, 32);
            float kA0 = pA0 + b30, kA1 = pA1 + b31, kA2 = pA2 + b32;
            float kB0 = pB0 + b30, kB1 = pB1 + b31, kB2 = pB2 + b32;

            const float ca = (st == 1 || st == 2) ? 2.0f : 1.0f;
            accA0 = fmaf(ca, kA0, accA0); accA1 = fmaf(ca, kA1, accA1); accA2 = fmaf(ca, kA2, accA2);
            accB0 = fmaf(ca, kB0, accB0); accB1 = fmaf(ca, kB1, accB1); accB2 = fmaf(ca, kB2, accB2);
            const float ci = (st == 2) ? dt : dt2;
            aA0 = fmaf(ci, kA0, yA0); aA1 = fmaf(ci, kA1, yA1); aA2 = fmaf(ci, kA2, yA2);
            aB0 = fmaf(ci, kB0, yB0); aB1 = fmaf(ci, kB1, yB1); aB2 = fmaf(ci, kB2, yB2);
        }
        yA0 = fmaf(dt6, accA0, yA0); yA1 = fmaf(dt6, accA1, yA1); yA2 = fmaf(dt6, accA2, yA2);
        yB0 = fmaf(dt6, accB0, yB0); yB1 = fmaf(dt6, accB1, yB1); yB2 = fmaf(dt6, accB2, yB2);

        // wave-uniform SALU fast path: most steps store nothing
        if ((smask >> s) & 1ull) {
            if (half == 0) {
#pragma unroll
                for (int j = 0; j < 8; ++j) {
                    if (sidx[j] == s) {
                        out[(size_t)j * B + rA] = fmaf(yA2, wo2, fmaf(yA1, wo1, fmaf(yA0, wo0, bo)));
                        out[(size_t)j * B + rB] = fmaf(yB2, wo2, fmaf(yB1, wo1, fmaf(yB0, wo0, bo)));
                    }
                }
            }
        }
    }
}

extern "C" void kernel_launch(void* const* d_in, const int* in_sizes, int n_in,
                              void* d_out, int out_size, void* d_ws, size_t ws_size,
                              hipStream_t stream) {
    const float* x       = (const float*)d_in[0];
    const float* samples = (const float*)d_in[1];
    const float* w1      = (const float*)d_in[2];
    const float* b1      = (const float*)d_in[3];
    const float* w2      = (const float*)d_in[4];
    const float* b2      = (const float*)d_in[5];
    const float* w3      = (const float*)d_in[6];
    const float* b3      = (const float*)d_in[7];
    const float* w_out   = (const float*)d_in[8];
    const float* b_out   = (const float*)d_in[9];
    float* out = (float*)d_out;

    const int B = in_sizes[0] / 3;           // 131072
    const int rowsPerBlock = 256;            // 4 waves x 64 rows (2 groups of 32)
    const int grid = (B + rowsPerBlock - 1) / rowsPerBlock;
    ode_rk4_mfma<<<grid, 256, 0, stream>>>(
        x, samples, w1, b1, w2, b2, w3, b3, w_out, b_out, out, B);
}